// Round 5
// baseline (4475.124 us; speedup 1.0000x reference)
//
#include <hip/hip_runtime.h>
#include <hip/hip_bf16.h>

#define DEPTH 24
#define DM 192
#define DI 384
#define DS 16
#define DR 12
#define LSEQ 401
#define BATCH 4
#define NTOK (BATCH*LSEQ)          // 1604
#define NCLS 22
#define NC 8                       // scan time-chunks
#define TCH 51                     // ceil(401/8); last chunk = 44

__device__ __forceinline__ float b2f(__hip_bfloat16 v) { return __bfloat162float(v); }
__device__ __forceinline__ float silu_f(float x) { return x / (1.f + __expf(-x)); }

// ---------------- input conversion: bf16-or-fp32 -> fp32 (single kernel) ----------------
struct CvtArgs { const void* src[19]; float* dst[19]; int n[19]; };

__global__ void cvt_all_k(CvtArgs a, const unsigned short* __restrict__ probe)
{
    int which = blockIdx.y;
    int n = a.n[which];
    float* dst = a.dst[which];
    bool bf = (probe[0] == 0x3F80u);
    int i = blockIdx.x * blockDim.x + threadIdx.x;
    int stride = gridDim.x * blockDim.x;
    if (bf) {
        const __hip_bfloat16* s = (const __hip_bfloat16*)a.src[which];
        for (; i < n; i += stride) dst[i] = b2f(s[i]);
    } else {
        const float* s = (const float*)a.src[which];
        for (; i < n; i += stride) dst[i] = s[i];
    }
}

// ---------------- patch embed + cls + pos; 4 tokens per block (pe_w reuse) ----------------
__global__ void patch_embed_k(const float* __restrict__ x,
                              const float* __restrict__ pe_w,
                              const float* __restrict__ pe_b,
                              const float* __restrict__ cls,
                              const float* __restrict__ pos,
                              float* __restrict__ residual, float* __restrict__ hidden)
{
    __shared__ float xp[4][256];
    int g0 = blockIdx.x * 4;
    int c = threadIdx.x;                  // 0..191
    #pragma unroll
    for (int j = 0; j < 4; j++) {
        int g = g0 + j;
        int b = g / LSEQ, t = g % LSEQ;
        if (t != 0) {
            int p = t - 1, pi = p / 200, pj = p % 200;
            for (int i = c; i < 256; i += 192) {
                int pp = i >> 4, qq = i & 15;
                xp[j][i] = x[((size_t)(b * 32 + pi * 16 + pp)) * 3200 + pj * 16 + qq];
            }
        }
    }
    __syncthreads();
    float acc[4] = {0.f, 0.f, 0.f, 0.f};
    for (int k = 0; k < 256; k++) {
        float w = pe_w[c * 256 + k];
        #pragma unroll
        for (int j = 0; j < 4; j++) acc[j] += xp[j][k] * w;
    }
    #pragma unroll
    for (int j = 0; j < 4; j++) {
        int g = g0 + j;
        int t = g % LSEQ;
        float v = (t == 0) ? cls[c] : (acc[j] + pe_b[c]);
        v += pos[t * DM + c];
        residual[(size_t)g * DM + c] = v;
        hidden[(size_t)g * DM + c] = v;
    }
}

// ---------------- fused prenorm + xz GEMM ----------------
// r = resin + hidden; resout = r (bn==0 blocks); hnorm = r*rms*nw (in LDS only);
// xz = hnorm @ ipw^T.  32x32 tile, full K=192 single stage. grid (24, 51).
__global__ __launch_bounds__(256) void xz_prenorm_k(
    const float* __restrict__ resin, const float* __restrict__ hidden,
    float* __restrict__ resout,
    const float* __restrict__ nw, const float* __restrict__ ipw,
    float* __restrict__ xz)
{
    __shared__ float As[DM][34];
    __shared__ float Ws[DM][34];
    int tid = threadIdx.x;
    int bn = blockIdx.x * 32;
    int bm = blockIdx.y * 32;
    int row8 = tid >> 3, seg = tid & 7, k0 = seg * 24;
    int m = bm + row8;
    float r[24];
    float s = 0.f;
    if (m < NTOK) {
        const float* rp = resin + (size_t)m * DM + k0;
        const float* hp = hidden + (size_t)m * DM + k0;
        #pragma unroll
        for (int i = 0; i < 24; i++) { r[i] = rp[i] + hp[i]; s += r[i] * r[i]; }
    } else {
        #pragma unroll
        for (int i = 0; i < 24; i++) r[i] = 0.f;
    }
    s += __shfl_down(s, 4, 8);
    s += __shfl_down(s, 2, 8);
    s += __shfl_down(s, 1, 8);
    float tot = __shfl(s, 0, 8);
    float rms = rsqrtf(tot / (float)DM + 1e-5f);
    if (bn == 0 && m < NTOK) {
        float* ro = resout + (size_t)m * DM + k0;
        #pragma unroll
        for (int i = 0; i < 24; i++) ro[i] = r[i];
    }
    #pragma unroll
    for (int i = 0; i < 24; i++)
        As[k0 + i][row8] = r[i] * rms * nw[k0 + i];
    {
        const float* wp = ipw + (size_t)(bn + row8) * DM + k0;
        #pragma unroll
        for (int i = 0; i < 24; i++) Ws[k0 + i][row8] = wp[i];
    }
    __syncthreads();
    int r0 = (tid >> 4) * 2, c0 = (tid & 15) * 2;
    float acc[2][2] = {};
    #pragma unroll 8
    for (int kk = 0; kk < DM; kk++) {
        float2 a = *(const float2*)&As[kk][r0];
        float2 w = *(const float2*)&Ws[kk][c0];
        acc[0][0] += a.x * w.x; acc[0][1] += a.x * w.y;
        acc[1][0] += a.y * w.x; acc[1][1] += a.y * w.y;
    }
    #pragma unroll
    for (int i = 0; i < 2; i++) {
        int mm = bm + r0 + i;
        if (mm >= NTOK) continue;
        #pragma unroll
        for (int j = 0; j < 2; j++)
            xz[(size_t)mm * (2 * DI) + bn + c0 + j] = acc[i][j];
    }
}

// ---------------- causal depthwise conv (K=4) + silu, both dirs; also zeroes dbl ----------------
__global__ void conv_silu_k(const float* __restrict__ xz,
                            const float* __restrict__ cw,
                            const float* __restrict__ cb,
                            float* __restrict__ xx,
                            float* __restrict__ dbl)
{
    int blk = blockIdx.x;                      // dir*B*L + b*L + t
    int dir = blk / (BATCH * LSEQ);
    int rem = blk % (BATCH * LSEQ);
    int b = rem / LSEQ, t = rem % LSEQ;
    int d = threadIdx.x;
    if (d < 44) dbl[(size_t)blk * 44 + d] = 0.f;   // zero for xproj atomics
    float s = cb[d];
    #pragma unroll
    for (int k = 0; k < 4; k++) {
        int tt = t - 3 + k;
        if (tt >= 0) {
            int st = dir ? (LSEQ - 1 - tt) : tt;
            s += cw[d * 4 + k] * xz[((size_t)(b * LSEQ + st)) * (2 * DI) + d];
        }
    }
    xx[(size_t)blk * DI + d] = silu_f(s);
}

// ---------------- xproj: dbl += xx @ xpw^T, split-K=4, atomic. grid (4, 101) ----------------
__global__ __launch_bounds__(256) void xproj_k(
    const float* __restrict__ xx, const float* __restrict__ xpw,
    float* __restrict__ dbl)
{
    __shared__ float As[96][33];
    __shared__ float Ws[96][48];
    int tid = threadIdx.x;
    int kbase = blockIdx.x * 96;
    int bm = blockIdx.y * 32;
    {
        int row = tid >> 3, seg = tid & 7;
        int m = bm + row;
        const float* ap = xx + (size_t)m * DI + kbase + seg * 12;
        #pragma unroll
        for (int i = 0; i < 12; i++)
            As[seg * 12 + i][row] = (m < 2 * NTOK) ? ap[i] : 0.f;
    }
    for (int i = tid; i < 96 * 48; i += 256) {
        int k = i / 48, rr = i % 48;
        Ws[k][rr] = (rr < 44) ? xpw[(size_t)rr * DI + kbase + k] : 0.f;
    }
    __syncthreads();
    int row = tid & 31, cg = tid >> 5;
    int cbase = cg * 6;
    float acc[6] = {};
    #pragma unroll 4
    for (int kk = 0; kk < 96; kk++) {
        float a = As[kk][row];
        #pragma unroll
        for (int j = 0; j < 6; j++) acc[j] += a * Ws[kk][cbase + j];
    }
    int m = bm + row;
    if (m < 2 * NTOK) {
        #pragma unroll
        for (int j = 0; j < 6; j++) {
            int cc = cbase + j;
            if (cc < 44) atomicAdd(&dbl[(size_t)m * 44 + cc], acc[j]);
        }
    }
}

// ---------------- dtproj: dt = softplus(dbl[:, :12] @ dtw^T + dtb). grid 802 ----------------
__global__ __launch_bounds__(256) void dtproj_k(
    const float* __restrict__ dbl, const float* __restrict__ dtw,
    const float* __restrict__ dtb, float* __restrict__ dt)
{
    __shared__ float wl[DI * 13];
    __shared__ float al[4][12];
    int tid = threadIdx.x;
    int m0 = blockIdx.x * 4;
    for (int i = tid; i < DI * 12; i += 256) {
        int col = i / 12, rr = i % 12;
        wl[col * 13 + rr] = dtw[i];
    }
    if (tid < 48) {
        int row = tid / 12, rr = tid % 12;
        al[row][rr] = dbl[(size_t)(m0 + row) * 44 + rr];
    }
    __syncthreads();
    #pragma unroll
    for (int j = 0; j < 6; j++) {
        int idx = j * 256 + tid;
        int row = idx / DI;
        int col = idx - row * DI;
        float s2 = dtb[col];
        #pragma unroll
        for (int rr = 0; rr < 12; rr++) s2 += al[row][rr] * wl[col * 13 + rr];
        s2 = (s2 > 15.f) ? s2 : __logf(1.f + __expf(s2));
        dt[(size_t)(m0 + row) * DI + col] = s2;
    }
}

// ---------------- chunked scan pass 1: local scan + chunk product (prefetch ring P=8) ----------------
__global__ __launch_bounds__(256) void scan_part_k(
    const float* __restrict__ dt, const float* __restrict__ xx,
    const float* __restrict__ dbl,
    const float* __restrict__ A_log, const float* __restrict__ A_b_log,
    float* __restrict__ hloc, float* __restrict__ Pc)
{
    int dblk = blockIdx.x, chunk = blockIdx.y;
    int db = blockIdx.z;                        // dir*BATCH + b
    int dir = db >> 2;
    int tid = threadIdx.x;
    int wave = tid >> 6, lane = tid & 63;
    int d = dblk * 16 + wave * 4 + (lane >> 4);
    int n = lane & 15;
    const float* Al = dir ? A_b_log : A_log;
    float Aval = -__expf(Al[d * DS + n]);
    size_t dofD = (size_t)db * LSEQ * DI;
    size_t dof44 = (size_t)db * LSEQ * 44;
    int t0 = chunk * TCH;
    const float* dtp = dt + dofD + d;
    const float* xxp = xx + dofD + d;
    const float* dblp = dbl + dof44 + DR + n;
    float pdt[8], px[8], pB[8];
    #pragma unroll
    for (int j = 0; j < 8; j++) {
        int tt = t0 + j;
        pdt[j] = dtp[(size_t)tt * DI];
        px[j]  = xxp[(size_t)tt * DI];
        pB[j]  = dblp[(size_t)tt * 44];
    }
    float h = 0.f, P = 1.f;
    #pragma unroll 8
    for (int i = 0; i < TCH; i++) {
        int sl = i & 7;
        float dtv = pdt[sl], xv = px[sl], Bv = pB[sl];
        int tn = t0 + i + 8;
        bool vld = (i + 8) < TCH;
        pdt[sl] = vld ? dtp[(size_t)tn * DI] : 0.f;
        px[sl]  = vld ? xxp[(size_t)tn * DI] : 0.f;
        pB[sl]  = vld ? dblp[(size_t)tn * 44] : 0.f;
        float dA = __expf(dtv * Aval);
        h = dA * h + (dtv * xv) * Bv;
        P *= dA;
    }
    size_t idx = ((size_t)db * NC + chunk) * (DI * DS) + (size_t)d * DS + n;
    hloc[idx] = h;
    Pc[idx] = P;
}

// ---------------- chunked scan pass 2: compose h_init, rescan, emit y; zero hidden ----------------
__global__ __launch_bounds__(256) void scan_fix_k(
    const float* __restrict__ dt, const float* __restrict__ xx,
    const float* __restrict__ dbl,
    const float* __restrict__ A_log, const float* __restrict__ A_b_log,
    const float* __restrict__ Dp,
    const float* __restrict__ hloc, const float* __restrict__ Pc,
    float* __restrict__ yraw, float* __restrict__ hidden)
{
    int tid = threadIdx.x;
    {   // zero hidden for outproj atomics (1536 blocks x 256 >= NTOK*DM)
        int gl = ((blockIdx.z * gridDim.y + blockIdx.y) * gridDim.x + blockIdx.x) * 256 + tid;
        if (gl < NTOK * DM) hidden[gl] = 0.f;
    }
    int dblk = blockIdx.x, chunk = blockIdx.y;
    int db = blockIdx.z;
    int dir = db >> 2;
    int wave = tid >> 6, lane = tid & 63;
    int d = dblk * 16 + wave * 4 + (lane >> 4);
    int n = lane & 15;
    const float* Al = dir ? A_b_log : A_log;
    float Aval = -__expf(Al[d * DS + n]);
    float Dv = Dp[d];
    size_t dofD = (size_t)db * LSEQ * DI;
    size_t dof44 = (size_t)db * LSEQ * 44;
    float h = 0.f;
    size_t cbase = (size_t)db * NC * (DI * DS) + (size_t)d * DS + n;
    for (int j = 0; j < chunk; j++) {
        size_t idx = cbase + (size_t)j * (DI * DS);
        h = Pc[idx] * h + hloc[idx];
    }
    int t0 = chunk * TCH;
    int len = min(t0 + TCH, LSEQ) - t0;
    const float* dtp = dt + dofD + d;
    const float* xxp = xx + dofD + d;
    const float* dblB = dbl + dof44 + DR + n;
    const float* dblC = dbl + dof44 + DR + DS + n;
    float* yp = yraw + dofD + d;
    float pdt[8], px[8], pB[8], pC[8];
    #pragma unroll
    for (int j = 0; j < 8; j++) {
        int tt = t0 + j;                      // always < LSEQ (357+7=364 max)
        pdt[j] = dtp[(size_t)tt * DI];
        px[j]  = xxp[(size_t)tt * DI];
        pB[j]  = dblB[(size_t)tt * 44];
        pC[j]  = dblC[(size_t)tt * 44];
    }
    #pragma unroll 8
    for (int i = 0; i < len; i++) {
        int sl = i & 7;
        float dtv = pdt[sl], xv = px[sl], Bv = pB[sl], Cv = pC[sl];
        int tn = t0 + i + 8;
        bool vld = (i + 8) < len;
        pdt[sl] = vld ? dtp[(size_t)tn * DI] : 0.f;
        px[sl]  = vld ? xxp[(size_t)tn * DI] : 0.f;
        pB[sl]  = vld ? dblB[(size_t)tn * 44] : 0.f;
        pC[sl]  = vld ? dblC[(size_t)tn * 44] : 0.f;
        h = __expf(dtv * Aval) * h + (dtv * xv) * Bv;
        float p = h * Cv;
        p += __shfl_xor(p, 1);
        p += __shfl_xor(p, 2);
        p += __shfl_xor(p, 4);
        p += __shfl_xor(p, 8);
        if (n == 0) yp[(size_t)(t0 + i) * DI] = p + xv * Dv;
    }
}

// ---------------- fused combine + outproj: hidden += [(yf+yb_rev)*silu(z)] @ opw^T ----------------
// 32x32 tile, split-K=2 (kz), full 192-K chunk in LDS. grid (6, 51, 2).
__global__ __launch_bounds__(256) void outproj_k(
    const float* __restrict__ yraw, const float* __restrict__ xz,
    const float* __restrict__ opw, float* __restrict__ hidden)
{
    __shared__ float As[192][34];
    __shared__ float Ws[192][34];
    int tid = threadIdx.x;
    int bn = blockIdx.x * 32;
    int bm = blockIdx.y * 32;
    int kbase = blockIdx.z * 192;
    int row8 = tid >> 3, seg = tid & 7, k0 = seg * 24;
    {
        int m = bm + row8;
        if (m < NTOK) {
            int b = m / LSEQ, t = m % LSEQ;
            const float* yf = yraw + (size_t)m * DI + kbase + k0;
            const float* yb = yraw + (size_t)(NTOK + b * LSEQ + (LSEQ - 1 - t)) * DI + kbase + k0;
            const float* zp = xz + (size_t)m * (2 * DI) + DI + kbase + k0;
            #pragma unroll
            for (int i = 0; i < 24; i++) {
                float z = zp[i];
                As[k0 + i][row8] = (yf[i] + yb[i]) * (z / (1.f + __expf(-z)));
            }
        } else {
            #pragma unroll
            for (int i = 0; i < 24; i++) As[k0 + i][row8] = 0.f;
        }
    }
    {
        const float* wp = opw + (size_t)(bn + row8) * DI + kbase + k0;
        #pragma unroll
        for (int i = 0; i < 24; i++) Ws[k0 + i][row8] = wp[i];
    }
    __syncthreads();
    int r0 = (tid >> 4) * 2, c0 = (tid & 15) * 2;
    float acc[2][2] = {};
    #pragma unroll 8
    for (int kk = 0; kk < 192; kk++) {
        float2 a = *(const float2*)&As[kk][r0];
        float2 w = *(const float2*)&Ws[kk][c0];
        acc[0][0] += a.x * w.x; acc[0][1] += a.x * w.y;
        acc[1][0] += a.y * w.x; acc[1][1] += a.y * w.y;
    }
    #pragma unroll
    for (int i = 0; i < 2; i++) {
        int m = bm + r0 + i;
        if (m >= NTOK) continue;
        #pragma unroll
        for (int j = 0; j < 2; j++)
            atomicAdd(&hidden[(size_t)m * DM + bn + c0 + j], acc[i][j]);
    }
}

// ---------------- final rmsnorm on token 0 + head (mode-switched output) ----------------
__global__ void final_head_k(const float* __restrict__ residual, const float* __restrict__ hidden,
                             const float* __restrict__ norm_f,
                             const float* __restrict__ head_w,
                             const float* __restrict__ head_b,
                             void* __restrict__ out,
                             const unsigned short* __restrict__ probe)
{
    __shared__ float wsum[3];
    __shared__ float hb[DM];
    int b = blockIdx.x;
    int c = threadIdx.x;
    int idx = (b * LSEQ) * DM + c;
    float r = residual[idx] + hidden[idx];
    float s = r * r;
    for (int off = 32; off > 0; off >>= 1) s += __shfl_down(s, off);
    int wave = c >> 6, lane = c & 63;
    if (lane == 0) wsum[wave] = s;
    __syncthreads();
    float tot = wsum[0] + wsum[1] + wsum[2];
    float rms = rsqrtf(tot / (float)DM + 1e-5f);
    hb[c] = r * rms * norm_f[c];
    __syncthreads();
    if (c < NCLS) {
        float acc = head_b[c];
        #pragma unroll 8
        for (int k = 0; k < DM; k++) acc += hb[k] * head_w[c * DM + k];
        if (probe[0] == 0x3F80u)
            ((__hip_bfloat16*)out)[b * NCLS + c] = __float2bfloat16(acc);
        else
            ((float*)out)[b * NCLS + c] = acc;
    }
}

extern "C" void kernel_launch(void* const* d_in, const int* in_sizes, int n_in,
                              void* d_out, int out_size, void* d_ws, size_t ws_size,
                              hipStream_t stream)
{
    (void)in_sizes; (void)n_in; (void)out_size; (void)ws_size;
    static const int IN_N[19] = {
        409600, 49152, 192, 192, 77184, 4608, 3538944, 36864, 9216,
        405504, 110592, 9216, 147456, 147456, 9216, 1769472, 192, 4224, 22
    };
    const unsigned short* probe = (const unsigned short*)d_in[14];  // Dp (=ones)

    float* ws = (float*)d_ws;
    float* F[19];
    size_t off = 0;
    for (int i = 0; i < 19; i++) { F[i] = ws + off; off += (size_t)IN_N[i]; }

    CvtArgs ca;
    for (int i = 0; i < 19; i++) { ca.src[i] = d_in[i]; ca.dst[i] = F[i]; ca.n[i] = IN_N[i]; }
    cvt_all_k<<<dim3(432, 19), 256, 0, stream>>>(ca, probe);

    const float* x      = F[0];
    const float* pe_w   = F[1];
    const float* pe_b   = F[2];
    const float* cls    = F[3];
    const float* pos    = F[4];
    const float* norm_w = F[5];
    const float* ipw    = F[6];
    const float* cw     = F[7];
    const float* cb     = F[8];
    const float* xpw    = F[9];
    const float* dtw    = F[10];
    const float* dtb    = F[11];
    const float* A_log  = F[12];
    const float* A_b_log= F[13];
    const float* Dp     = F[14];
    const float* opw    = F[15];
    const float* norm_f = F[16];
    const float* head_w = F[17];
    const float* head_b = F[18];

    const size_t nTokDM = (size_t)NTOK * DM;
    const size_t nTokXZ = (size_t)NTOK * 2 * DI;
    const size_t nDirDI = (size_t)2 * NTOK * DI;
    const size_t nDir44 = (size_t)2 * NTOK * 44;
    const size_t nChunk = (size_t)2 * BATCH * NC * DI * DS;
    float* resA   = ws + off;
    float* resB   = resA + nTokDM;
    float* hidden = resB + nTokDM;
    float* xz     = hidden + nTokDM;
    float* xx     = xz + nTokXZ;
    float* dbl    = xx + nDirDI;
    float* dt     = dbl + nDir44;
    float* yraw   = dt + nDirDI;
    float* hloc   = yraw + nDirDI;
    float* Pc     = hloc + nChunk;

    patch_embed_k<<<NTOK / 4, DM, 0, stream>>>(x, pe_w, pe_b, cls, pos, resA, hidden);

    for (int l = 0; l < DEPTH; l++) {
        float* rin  = (l & 1) ? resB : resA;
        float* rout = (l & 1) ? resA : resB;

        xz_prenorm_k<<<dim3(24, 51), 256, 0, stream>>>(
            rin, hidden, rout, norm_w + (size_t)l * DM,
            ipw + (size_t)l * 2 * DI * DM, xz);

        conv_silu_k<<<2 * NTOK, DI, 0, stream>>>(
            xz, cw + (size_t)l * DI * 4, cb + (size_t)l * DI, xx, dbl);

        xproj_k<<<dim3(4, 101), 256, 0, stream>>>(
            xx, xpw + (size_t)l * 44 * DI, dbl);

        dtproj_k<<<802, 256, 0, stream>>>(
            dbl, dtw + (size_t)l * DI * DR, dtb + (size_t)l * DI, dt);

        scan_part_k<<<dim3(DI / 16, NC - 1, 2 * BATCH), 256, 0, stream>>>(
            dt, xx, dbl,
            A_log + (size_t)l * DI * DS, A_b_log + (size_t)l * DI * DS,
            hloc, Pc);

        scan_fix_k<<<dim3(DI / 16, NC, 2 * BATCH), 256, 0, stream>>>(
            dt, xx, dbl,
            A_log + (size_t)l * DI * DS, A_b_log + (size_t)l * DI * DS,
            Dp + (size_t)l * DI, hloc, Pc, yraw, hidden);

        outproj_k<<<dim3(6, 51, 2), 256, 0, stream>>>(
            yraw, xz, opw + (size_t)l * DM * DI, hidden);
    }

    // after 24 layers (even count), final residual is resA
    final_head_k<<<BATCH, DM, 0, stream>>>(resA, hidden, norm_f, head_w, head_b,
                                           d_out, probe);
}

// Round 6
// 3171.101 us; speedup vs baseline: 1.4112x; 1.4112x over previous
//
#include <hip/hip_runtime.h>
#include <hip/hip_bf16.h>

#define DEPTH 24
#define DM 192
#define DI 384
#define DS 16
#define DR 12
#define LSEQ 401
#define BATCH 4
#define NTOK (BATCH*LSEQ)          // 1604
#define NCLS 22
#define NC 16                      // scan time-chunks
#define TCH 26                     // ceil(401/16); last chunk = 11

__device__ __forceinline__ float b2f(__hip_bfloat16 v) { return __bfloat162float(v); }
__device__ __forceinline__ float silu_f(float x) { return x / (1.f + __expf(-x)); }

// ---------------- input conversion: bf16-or-fp32 -> fp32 (single kernel) ----------------
struct CvtArgs { const void* src[19]; float* dst[19]; int n[19]; };

__global__ void cvt_all_k(CvtArgs a, const unsigned short* __restrict__ probe)
{
    int which = blockIdx.y;
    int n = a.n[which];
    float* dst = a.dst[which];
    bool bf = (probe[0] == 0x3F80u);
    int i = blockIdx.x * blockDim.x + threadIdx.x;
    int stride = gridDim.x * blockDim.x;
    if (bf) {
        const __hip_bfloat16* s = (const __hip_bfloat16*)a.src[which];
        for (; i < n; i += stride) dst[i] = b2f(s[i]);
    } else {
        const float* s = (const float*)a.src[which];
        for (; i < n; i += stride) dst[i] = s[i];
    }
}

// ---------------- patch embed + cls + pos; 4 tokens per block (pe_w reuse) ----------------
__global__ void patch_embed_k(const float* __restrict__ x,
                              const float* __restrict__ pe_w,
                              const float* __restrict__ pe_b,
                              const float* __restrict__ cls,
                              const float* __restrict__ pos,
                              float* __restrict__ residual, float* __restrict__ hidden)
{
    __shared__ float xp[4][256];
    int g0 = blockIdx.x * 4;
    int c = threadIdx.x;                  // 0..191
    #pragma unroll
    for (int j = 0; j < 4; j++) {
        int g = g0 + j;
        int b = g / LSEQ, t = g % LSEQ;
        if (t != 0) {
            int p = t - 1, pi = p / 200, pj = p % 200;
            for (int i = c; i < 256; i += 192) {
                int pp = i >> 4, qq = i & 15;
                xp[j][i] = x[((size_t)(b * 32 + pi * 16 + pp)) * 3200 + pj * 16 + qq];
            }
        }
    }
    __syncthreads();
    float acc[4] = {0.f, 0.f, 0.f, 0.f};
    for (int k = 0; k < 256; k++) {
        float w = pe_w[c * 256 + k];
        #pragma unroll
        for (int j = 0; j < 4; j++) acc[j] += xp[j][k] * w;
    }
    #pragma unroll
    for (int j = 0; j < 4; j++) {
        int g = g0 + j;
        int t = g % LSEQ;
        float v = (t == 0) ? cls[c] : (acc[j] + pe_b[c]);
        v += pos[t * DM + c];
        residual[(size_t)g * DM + c] = v;
        hidden[(size_t)g * DM + c] = v;
    }
}

// ---------------- fused prenorm + xz GEMM, 2-stage K (LDS 26KB) ----------------
// r = resin + hidden; resout = r (bn==0 blocks); xz = rmsnorm(r)*nw @ ipw^T.
// 32x32 tile. grid (24, 51).
__global__ __launch_bounds__(256) void xz_prenorm_k(
    const float* __restrict__ resin, const float* __restrict__ hidden,
    float* __restrict__ resout,
    const float* __restrict__ nw, const float* __restrict__ ipw,
    float* __restrict__ xz)
{
    __shared__ float As[96][34];
    __shared__ float Ws[96][34];
    int tid = threadIdx.x;
    int bn = blockIdx.x * 32;
    int bm = blockIdx.y * 32;
    int row8 = tid >> 3, seg = tid & 7, k0 = seg * 24;
    int m = bm + row8;
    float r[24];
    float s = 0.f;
    if (m < NTOK) {
        const float* rp = resin + (size_t)m * DM + k0;
        const float* hp = hidden + (size_t)m * DM + k0;
        #pragma unroll
        for (int i = 0; i < 24; i++) { r[i] = rp[i] + hp[i]; s += r[i] * r[i]; }
    } else {
        #pragma unroll
        for (int i = 0; i < 24; i++) r[i] = 0.f;
    }
    s += __shfl_down(s, 4, 8);
    s += __shfl_down(s, 2, 8);
    s += __shfl_down(s, 1, 8);
    float tot = __shfl(s, 0, 8);
    float rms = rsqrtf(tot / (float)DM + 1e-5f);
    if (bn == 0 && m < NTOK) {
        float* ro = resout + (size_t)m * DM + k0;
        #pragma unroll
        for (int i = 0; i < 24; i++) ro[i] = r[i];
    }
    float av[24], wreg[24];
    {
        const float* wp = ipw + (size_t)(bn + row8) * DM + k0;
        #pragma unroll
        for (int i = 0; i < 24; i++) {
            av[i] = r[i] * rms * nw[k0 + i];
            wreg[i] = wp[i];
        }
    }
    int r0 = (tid >> 4) * 2, c0 = (tid & 15) * 2;
    float acc[2][2] = {};
    #pragma unroll
    for (int st = 0; st < 2; st++) {
        if (st) __syncthreads();
        if ((seg >> 2) == st) {
            int kb = k0 - st * 96;
            #pragma unroll
            for (int i = 0; i < 24; i++) {
                As[kb + i][row8] = av[i];
                Ws[kb + i][row8] = wreg[i];
            }
        }
        __syncthreads();
        #pragma unroll 8
        for (int kk = 0; kk < 96; kk++) {
            float2 a = *(const float2*)&As[kk][r0];
            float2 w = *(const float2*)&Ws[kk][c0];
            acc[0][0] += a.x * w.x; acc[0][1] += a.x * w.y;
            acc[1][0] += a.y * w.x; acc[1][1] += a.y * w.y;
        }
    }
    #pragma unroll
    for (int i = 0; i < 2; i++) {
        int mm = bm + r0 + i;
        if (mm >= NTOK) continue;
        #pragma unroll
        for (int j = 0; j < 2; j++)
            xz[(size_t)mm * (2 * DI) + bn + c0 + j] = acc[i][j];
    }
}

// ---------------- causal depthwise conv (K=4) + silu, both dirs; also zeroes dbl ----------------
__global__ void conv_silu_k(const float* __restrict__ xz,
                            const float* __restrict__ cw,
                            const float* __restrict__ cb,
                            float* __restrict__ xx,
                            float* __restrict__ dbl)
{
    int blk = blockIdx.x;                      // dir*B*L + b*L + t
    int dir = blk / (BATCH * LSEQ);
    int rem = blk % (BATCH * LSEQ);
    int b = rem / LSEQ, t = rem % LSEQ;
    int d = threadIdx.x;
    if (d < 44) dbl[(size_t)blk * 44 + d] = 0.f;   // zero for xproj atomics
    float s = cb[d];
    #pragma unroll
    for (int k = 0; k < 4; k++) {
        int tt = t - 3 + k;
        if (tt >= 0) {
            int st = dir ? (LSEQ - 1 - tt) : tt;
            s += cw[d * 4 + k] * xz[((size_t)(b * LSEQ + st)) * (2 * DI) + d];
        }
    }
    xx[(size_t)blk * DI + d] = silu_f(s);
}

// ---------------- xproj: dbl += xx @ xpw^T, split-K=4, atomic. grid (4, 101) ----------------
__global__ __launch_bounds__(256) void xproj_k(
    const float* __restrict__ xx, const float* __restrict__ xpw,
    float* __restrict__ dbl)
{
    __shared__ float As[96][33];
    __shared__ float Ws[96][48];
    int tid = threadIdx.x;
    int kbase = blockIdx.x * 96;
    int bm = blockIdx.y * 32;
    {
        int row = tid >> 3, seg = tid & 7;
        int m = bm + row;
        const float* ap = xx + (size_t)m * DI + kbase + seg * 12;
        #pragma unroll
        for (int i = 0; i < 12; i++)
            As[seg * 12 + i][row] = (m < 2 * NTOK) ? ap[i] : 0.f;
    }
    for (int i = tid; i < 96 * 48; i += 256) {
        int k = i / 48, rr = i % 48;
        Ws[k][rr] = (rr < 44) ? xpw[(size_t)rr * DI + kbase + k] : 0.f;
    }
    __syncthreads();
    int row = tid & 31, cg = tid >> 5;
    int cbase = cg * 6;
    float acc[6] = {};
    #pragma unroll 4
    for (int kk = 0; kk < 96; kk++) {
        float a = As[kk][row];
        #pragma unroll
        for (int j = 0; j < 6; j++) acc[j] += a * Ws[kk][cbase + j];
    }
    int m = bm + row;
    if (m < 2 * NTOK) {
        #pragma unroll
        for (int j = 0; j < 6; j++) {
            int cc = cbase + j;
            if (cc < 44) atomicAdd(&dbl[(size_t)m * 44 + cc], acc[j]);
        }
    }
}

// ---------------- dtproj: dt = softplus(dbl[:, :12] @ dtw^T + dtb). grid 802 ----------------
__global__ __launch_bounds__(256) void dtproj_k(
    const float* __restrict__ dbl, const float* __restrict__ dtw,
    const float* __restrict__ dtb, float* __restrict__ dt)
{
    __shared__ float wl[DI * 13];
    __shared__ float al[4][12];
    int tid = threadIdx.x;
    int m0 = blockIdx.x * 4;
    for (int i = tid; i < DI * 12; i += 256) {
        int col = i / 12, rr = i % 12;
        wl[col * 13 + rr] = dtw[i];
    }
    if (tid < 48) {
        int row = tid / 12, rr = tid % 12;
        al[row][rr] = dbl[(size_t)(m0 + row) * 44 + rr];
    }
    __syncthreads();
    #pragma unroll
    for (int j = 0; j < 6; j++) {
        int idx = j * 256 + tid;
        int row = idx / DI;
        int col = idx - row * DI;
        float s2 = dtb[col];
        #pragma unroll
        for (int rr = 0; rr < 12; rr++) s2 += al[row][rr] * wl[col * 13 + rr];
        s2 = (s2 > 15.f) ? s2 : __logf(1.f + __expf(s2));
        dt[(size_t)(m0 + row) * DI + col] = s2;
    }
}

// ---------------- chunked scan pass 1: LDS-staged local scan + chunk product ----------------
// grid (24, NC-1, 8), block 256 = 16 d x 16 n. All chunks full (TCH steps).
__global__ __launch_bounds__(256) void scan_part_k(
    const float* __restrict__ dt, const float* __restrict__ xx,
    const float* __restrict__ dbl,
    const float* __restrict__ A_log, const float* __restrict__ A_b_log,
    float* __restrict__ hloc, float* __restrict__ Pc)
{
    __shared__ float sdt[TCH][16];
    __shared__ float sxx[TCH][16];
    __shared__ float sB[TCH][16];
    int dblk = blockIdx.x, chunk = blockIdx.y;
    int db = blockIdx.z;                        // dir*BATCH + b
    int dir = db >> 2;
    int tid = threadIdx.x;
    int d0 = dblk * 16;
    int t0 = chunk * TCH;
    size_t dofD = (size_t)db * LSEQ * DI;
    size_t dof44 = (size_t)db * LSEQ * 44;
    for (int idx = tid; idx < TCH * 16; idx += 256) {
        int t = idx >> 4, d = idx & 15;
        size_t g = dofD + (size_t)(t0 + t) * DI + d0 + d;
        sdt[t][d] = dt[g];
        sxx[t][d] = xx[g];
        sB[t][d] = dbl[dof44 + (size_t)(t0 + t) * 44 + DR + d];
    }
    __syncthreads();
    int wave = tid >> 6, lane = tid & 63;
    int dsub = wave * 4 + (lane >> 4);
    int n = lane & 15;
    const float* Al = dir ? A_b_log : A_log;
    float Aval = -__expf(Al[(d0 + dsub) * DS + n]);
    float h = 0.f, P = 1.f;
    #pragma unroll
    for (int i = 0; i < TCH; i++) {
        float dtv = sdt[i][dsub];
        float xv  = sxx[i][dsub];
        float Bv  = sB[i][n];
        float dA = __expf(dtv * Aval);
        h = dA * h + (dtv * xv) * Bv;
        P *= dA;
    }
    size_t idx2 = ((size_t)db * NC + chunk) * (DI * DS) + (size_t)(d0 + dsub) * DS + n;
    hloc[idx2] = h;
    Pc[idx2] = P;
}

// ---------------- chunked scan pass 2: compose h_init, LDS-staged rescan, emit y ----------------
// grid (24, NC, 8). Also zeroes `hidden` for outproj atomics.
__global__ __launch_bounds__(256) void scan_fix_k(
    const float* __restrict__ dt, const float* __restrict__ xx,
    const float* __restrict__ dbl,
    const float* __restrict__ A_log, const float* __restrict__ A_b_log,
    const float* __restrict__ Dp,
    const float* __restrict__ hloc, const float* __restrict__ Pc,
    float* __restrict__ yraw, float* __restrict__ hidden)
{
    __shared__ float sdt[TCH][16];
    __shared__ float sxx[TCH][16];
    __shared__ float sBC[TCH][32];
    __shared__ float sy[TCH][16];
    int tid = threadIdx.x;
    {   // zero hidden for outproj atomics (3072 blocks x 256 >= NTOK*DM)
        int gl = ((blockIdx.z * gridDim.y + blockIdx.y) * gridDim.x + blockIdx.x) * 256 + tid;
        if (gl < NTOK * DM) hidden[gl] = 0.f;
    }
    int dblk = blockIdx.x, chunk = blockIdx.y;
    int db = blockIdx.z;
    int dir = db >> 2;
    int d0 = dblk * 16;
    int t0 = chunk * TCH;
    size_t dofD = (size_t)db * LSEQ * DI;
    size_t dof44 = (size_t)db * LSEQ * 44;
    for (int idx = tid; idx < TCH * 16; idx += 256) {
        int t = idx >> 4, d = idx & 15;
        bool v = (t0 + t) < LSEQ;
        size_t g = dofD + (size_t)(t0 + t) * DI + d0 + d;
        size_t g44 = dof44 + (size_t)(t0 + t) * 44 + DR;
        sdt[t][d]      = v ? dt[g] : 0.f;
        sxx[t][d]      = v ? xx[g] : 0.f;
        sBC[t][d]      = v ? dbl[g44 + d] : 0.f;
        sBC[t][16 + d] = v ? dbl[g44 + 16 + d] : 0.f;
    }
    __syncthreads();
    int wave = tid >> 6, lane = tid & 63;
    int dsub = wave * 4 + (lane >> 4);
    int n = lane & 15;
    const float* Al = dir ? A_b_log : A_log;
    float Aval = -__expf(Al[(d0 + dsub) * DS + n]);
    float Dv = Dp[d0 + dsub];
    float h = 0.f;
    size_t cbase = (size_t)db * NC * (DI * DS) + (size_t)(d0 + dsub) * DS + n;
    for (int j = 0; j < chunk; j++) {
        size_t idx = cbase + (size_t)j * (DI * DS);
        h = Pc[idx] * h + hloc[idx];
    }
    #pragma unroll
    for (int i = 0; i < TCH; i++) {
        float dtv = sdt[i][dsub];
        float xv  = sxx[i][dsub];
        float Bv  = sBC[i][n];
        float Cv  = sBC[i][16 + n];
        h = __expf(dtv * Aval) * h + (dtv * xv) * Bv;
        float p = h * Cv;
        p += __shfl_xor(p, 1);
        p += __shfl_xor(p, 2);
        p += __shfl_xor(p, 4);
        p += __shfl_xor(p, 8);
        if (n == 0) sy[i][dsub] = p + xv * Dv;
    }
    __syncthreads();
    int len = min(t0 + TCH, LSEQ) - t0;
    for (int idx = tid; idx < len * 16; idx += 256) {
        int t = idx >> 4, d = idx & 15;
        yraw[dofD + (size_t)(t0 + t) * DI + d0 + d] = sy[t][d];
    }
}

// ---------------- fused combine + outproj, 2-stage K (LDS 26KB) ----------------
// hidden += [(yf+yb_rev)*silu(z)] @ opw^T. 32x32 tile, split-K=2. grid (6, 51, 2).
__global__ __launch_bounds__(256) void outproj_k(
    const float* __restrict__ yraw, const float* __restrict__ xz,
    const float* __restrict__ opw, float* __restrict__ hidden)
{
    __shared__ float As[96][34];
    __shared__ float Ws[96][34];
    int tid = threadIdx.x;
    int bn = blockIdx.x * 32;
    int bm = blockIdx.y * 32;
    int kbase = blockIdx.z * 192;
    int row8 = tid >> 3, seg = tid & 7, k0 = seg * 24;
    float a[24], wreg[24];
    int m = bm + row8;
    if (m < NTOK) {
        int b = m / LSEQ, t = m % LSEQ;
        const float* yf = yraw + (size_t)m * DI + kbase + k0;
        const float* yb = yraw + (size_t)(NTOK + b * LSEQ + (LSEQ - 1 - t)) * DI + kbase + k0;
        const float* zp = xz + (size_t)m * (2 * DI) + DI + kbase + k0;
        #pragma unroll
        for (int i = 0; i < 24; i++) {
            float z = zp[i];
            a[i] = (yf[i] + yb[i]) * (z / (1.f + __expf(-z)));
        }
    } else {
        #pragma unroll
        for (int i = 0; i < 24; i++) a[i] = 0.f;
    }
    {
        const float* wp = opw + (size_t)(bn + row8) * DI + kbase + k0;
        #pragma unroll
        for (int i = 0; i < 24; i++) wreg[i] = wp[i];
    }
    int r0 = (tid >> 4) * 2, c0 = (tid & 15) * 2;
    float acc[2][2] = {};
    #pragma unroll
    for (int st = 0; st < 2; st++) {
        if (st) __syncthreads();
        if ((seg >> 2) == st) {
            int kb = k0 - st * 96;
            #pragma unroll
            for (int i = 0; i < 24; i++) {
                As[kb + i][row8] = a[i];
                Ws[kb + i][row8] = wreg[i];
            }
        }
        __syncthreads();
        #pragma unroll 8
        for (int kk = 0; kk < 96; kk++) {
            float2 av = *(const float2*)&As[kk][r0];
            float2 wv = *(const float2*)&Ws[kk][c0];
            acc[0][0] += av.x * wv.x; acc[0][1] += av.x * wv.y;
            acc[1][0] += av.y * wv.x; acc[1][1] += av.y * wv.y;
        }
    }
    #pragma unroll
    for (int i = 0; i < 2; i++) {
        int mm = bm + r0 + i;
        if (mm >= NTOK) continue;
        #pragma unroll
        for (int j = 0; j < 2; j++)
            atomicAdd(&hidden[(size_t)mm * DM + bn + c0 + j], acc[i][j]);
    }
}

// ---------------- final rmsnorm on token 0 + head (mode-switched output) ----------------
__global__ void final_head_k(const float* __restrict__ residual, const float* __restrict__ hidden,
                             const float* __restrict__ norm_f,
                             const float* __restrict__ head_w,
                             const float* __restrict__ head_b,
                             void* __restrict__ out,
                             const unsigned short* __restrict__ probe)
{
    __shared__ float wsum[3];
    __shared__ float hb[DM];
    int b = blockIdx.x;
    int c = threadIdx.x;
    int idx = (b * LSEQ) * DM + c;
    float r = residual[idx] + hidden[idx];
    float s = r * r;
    for (int off = 32; off > 0; off >>= 1) s += __shfl_down(s, off);
    int wave = c >> 6, lane = c & 63;
    if (lane == 0) wsum[wave] = s;
    __syncthreads();
    float tot = wsum[0] + wsum[1] + wsum[2];
    float rms = rsqrtf(tot / (float)DM + 1e-5f);
    hb[c] = r * rms * norm_f[c];
    __syncthreads();
    if (c < NCLS) {
        float acc = head_b[c];
        #pragma unroll 8
        for (int k = 0; k < DM; k++) acc += hb[k] * head_w[c * DM + k];
        if (probe[0] == 0x3F80u)
            ((__hip_bfloat16*)out)[b * NCLS + c] = __float2bfloat16(acc);
        else
            ((float*)out)[b * NCLS + c] = acc;
    }
}

extern "C" void kernel_launch(void* const* d_in, const int* in_sizes, int n_in,
                              void* d_out, int out_size, void* d_ws, size_t ws_size,
                              hipStream_t stream)
{
    (void)in_sizes; (void)n_in; (void)out_size; (void)ws_size;
    static const int IN_N[19] = {
        409600, 49152, 192, 192, 77184, 4608, 3538944, 36864, 9216,
        405504, 110592, 9216, 147456, 147456, 9216, 1769472, 192, 4224, 22
    };
    const unsigned short* probe = (const unsigned short*)d_in[14];  // Dp (=ones)

    float* ws = (float*)d_ws;
    float* F[19];
    size_t off = 0;
    for (int i = 0; i < 19; i++) { F[i] = ws + off; off += (size_t)IN_N[i]; }

    CvtArgs ca;
    for (int i = 0; i < 19; i++) { ca.src[i] = d_in[i]; ca.dst[i] = F[i]; ca.n[i] = IN_N[i]; }
    cvt_all_k<<<dim3(432, 19), 256, 0, stream>>>(ca, probe);

    const float* x      = F[0];
    const float* pe_w   = F[1];
    const float* pe_b   = F[2];
    const float* cls    = F[3];
    const float* pos    = F[4];
    const float* norm_w = F[5];
    const float* ipw    = F[6];
    const float* cw     = F[7];
    const float* cb     = F[8];
    const float* xpw    = F[9];
    const float* dtw    = F[10];
    const float* dtb    = F[11];
    const float* A_log  = F[12];
    const float* A_b_log= F[13];
    const float* Dp     = F[14];
    const float* opw    = F[15];
    const float* norm_f = F[16];
    const float* head_w = F[17];
    const float* head_b = F[18];

    const size_t nTokDM = (size_t)NTOK * DM;
    const size_t nTokXZ = (size_t)NTOK * 2 * DI;
    const size_t nDirDI = (size_t)2 * NTOK * DI;
    const size_t nDir44 = (size_t)2 * NTOK * 44;
    const size_t nChunk = (size_t)2 * BATCH * NC * DI * DS;  // 786432
    float* resA   = ws + off;
    float* resB   = resA + nTokDM;
    float* hidden = resB + nTokDM;
    float* xz     = hidden + nTokDM;
    float* xx     = xz + nTokXZ;
    float* dbl    = xx + nDirDI;
    float* dt     = dbl + nDir44;
    float* yraw   = dt + nDirDI;
    float* hloc   = yraw + nDirDI;
    float* Pc     = hloc + nChunk;

    patch_embed_k<<<NTOK / 4, DM, 0, stream>>>(x, pe_w, pe_b, cls, pos, resA, hidden);

    for (int l = 0; l < DEPTH; l++) {
        float* rin  = (l & 1) ? resB : resA;
        float* rout = (l & 1) ? resA : resB;

        xz_prenorm_k<<<dim3(24, 51), 256, 0, stream>>>(
            rin, hidden, rout, norm_w + (size_t)l * DM,
            ipw + (size_t)l * 2 * DI * DM, xz);

        conv_silu_k<<<2 * NTOK, DI, 0, stream>>>(
            xz, cw + (size_t)l * DI * 4, cb + (size_t)l * DI, xx, dbl);

        xproj_k<<<dim3(4, 101), 256, 0, stream>>>(
            xx, xpw + (size_t)l * 44 * DI, dbl);

        dtproj_k<<<802, 256, 0, stream>>>(
            dbl, dtw + (size_t)l * DI * DR, dtb + (size_t)l * DI, dt);

        scan_part_k<<<dim3(DI / 16, NC - 1, 2 * BATCH), 256, 0, stream>>>(
            dt, xx, dbl,
            A_log + (size_t)l * DI * DS, A_b_log + (size_t)l * DI * DS,
            hloc, Pc);

        scan_fix_k<<<dim3(DI / 16, NC, 2 * BATCH), 256, 0, stream>>>(
            dt, xx, dbl,
            A_log + (size_t)l * DI * DS, A_b_log + (size_t)l * DI * DS,
            Dp + (size_t)l * DI, hloc, Pc, yraw, hidden);

        outproj_k<<<dim3(6, 51, 2), 256, 0, stream>>>(
            yraw, xz, opw + (size_t)l * DM * DI, hidden);
    }

    // after 24 layers (even count), final residual is resA
    final_head_k<<<BATCH, DM, 0, stream>>>(resA, hidden, norm_f, head_w, head_b,
                                           d_out, probe);
}

// Round 7
// 3068.498 us; speedup vs baseline: 1.4584x; 1.0334x over previous
//
#include <hip/hip_runtime.h>
#include <hip/hip_bf16.h>

#define DEPTH 24
#define DM 192
#define DI 384
#define DS 16
#define DR 12
#define LSEQ 401
#define BATCH 4
#define NTOK (BATCH*LSEQ)          // 1604
#define NCLS 22
#define NC 16                      // scan time-chunks
#define TCH 26                     // ceil(401/16); last chunk = 11

__device__ __forceinline__ float silu_f(float x) { return x / (1.f + __expf(-x)); }

// ---------------- patch embed + cls + pos; 4 tokens per block ----------------
__global__ void patch_embed_k(const float* __restrict__ x,
                              const float* __restrict__ pe_w,
                              const float* __restrict__ pe_b,
                              const float* __restrict__ cls,
                              const float* __restrict__ pos,
                              float* __restrict__ residual, float* __restrict__ hidden)
{
    __shared__ float xp[4][256];
    int g0 = blockIdx.x * 4;
    int c = threadIdx.x;                  // 0..191
    #pragma unroll
    for (int j = 0; j < 4; j++) {
        int g = g0 + j;
        int b = g / LSEQ, t = g % LSEQ;
        if (t != 0) {
            int p = t - 1, pi = p / 200, pj = p % 200;
            for (int i = c; i < 256; i += 192) {
                int pp = i >> 4, qq = i & 15;
                xp[j][i] = x[((size_t)(b * 32 + pi * 16 + pp)) * 3200 + pj * 16 + qq];
            }
        }
    }
    __syncthreads();
    float acc[4] = {0.f, 0.f, 0.f, 0.f};
    for (int k = 0; k < 256; k++) {
        float w = pe_w[c * 256 + k];
        #pragma unroll
        for (int j = 0; j < 4; j++) acc[j] += xp[j][k] * w;
    }
    #pragma unroll
    for (int j = 0; j < 4; j++) {
        int g = g0 + j;
        int t = g % LSEQ;
        float v = (t == 0) ? cls[c] : (acc[j] + pe_b[c]);
        v += pos[t * DM + c];
        residual[(size_t)g * DM + c] = v;
        hidden[(size_t)g * DM + c] = v;
    }
}

// ---------------- prenorm: r=rin+hidden; resout=r; hnorm=r*rms*nw; hidden=0; dbl=0 ----------------
// 401 blocks x 192 threads, 4 tokens each
__global__ __launch_bounds__(192) void prenorm_k(
    const float* __restrict__ resin, float* __restrict__ hidden,
    float* __restrict__ resout, float* __restrict__ hnorm,
    const float* __restrict__ nw, float* __restrict__ dbl)
{
    __shared__ float wsum[3][4];
    int c = threadIdx.x;
    int t0 = blockIdx.x * 4;
    int wave = c >> 6, lane = c & 63;
    float r[4], s[4];
    #pragma unroll
    for (int j = 0; j < 4; j++) {
        int idx = (t0 + j) * DM + c;
        r[j] = resin[idx] + hidden[idx];
        s[j] = r[j] * r[j];
    }
    #pragma unroll
    for (int off = 32; off > 0; off >>= 1) {
        #pragma unroll
        for (int j = 0; j < 4; j++) s[j] += __shfl_down(s[j], off);
    }
    if (lane == 0) {
        #pragma unroll
        for (int j = 0; j < 4; j++) wsum[wave][j] = s[j];
    }
    __syncthreads();
    float nwv = nw[c];
    #pragma unroll
    for (int j = 0; j < 4; j++) {
        float tot = wsum[0][j] + wsum[1][j] + wsum[2][j];
        float rms = rsqrtf(tot / (float)DM + 1e-5f);
        int idx = (t0 + j) * DM + c;
        resout[idx] = r[j];
        hnorm[idx] = r[j] * rms * nwv;
        hidden[idx] = 0.f;                 // for outproj atomics
    }
    for (int i = blockIdx.x * 192 + c; i < 2 * NTOK * 44; i += 401 * 192)
        dbl[i] = 0.f;                      // for xproj atomics
}

// ---------------- xz GEMM: xz = hnorm @ ipw^T. 64x64 tile, 4x4/thread, KS=48 ----------------
__global__ __launch_bounds__(256) void gemm_xz_k(
    const float* __restrict__ hnorm, const float* __restrict__ ipw,
    float* __restrict__ xz)
{
    constexpr int KS = 48;
    __shared__ float As[KS][68];
    __shared__ float Ws[KS][68];
    int tid = threadIdx.x;
    int bn = blockIdx.x * 64;
    int bm = blockIdx.y * 64;
    int r0 = (tid >> 4) * 4;
    int c0 = (tid & 15) * 4;
    int srow = tid >> 2, sk = (tid & 3) * 12;
    float acc[4][4] = {};
    for (int k0 = 0; k0 < DM; k0 += KS) {
        {
            int m = bm + srow;
            const float* ap = hnorm + (size_t)m * DM + k0 + sk;
            #pragma unroll
            for (int i = 0; i < 12; i++)
                As[sk + i][srow] = (m < NTOK) ? ap[i] : 0.f;
            const float* wp = ipw + (size_t)(bn + srow) * DM + k0 + sk;
            #pragma unroll
            for (int i = 0; i < 12; i++)
                Ws[sk + i][srow] = wp[i];
        }
        __syncthreads();
        #pragma unroll
        for (int kk = 0; kk < KS; kk++) {
            float4 a = *(const float4*)&As[kk][r0];
            float4 w = *(const float4*)&Ws[kk][c0];
            acc[0][0] += a.x * w.x; acc[0][1] += a.x * w.y; acc[0][2] += a.x * w.z; acc[0][3] += a.x * w.w;
            acc[1][0] += a.y * w.x; acc[1][1] += a.y * w.y; acc[1][2] += a.y * w.z; acc[1][3] += a.y * w.w;
            acc[2][0] += a.z * w.x; acc[2][1] += a.z * w.y; acc[2][2] += a.z * w.z; acc[2][3] += a.z * w.w;
            acc[3][0] += a.w * w.x; acc[3][1] += a.w * w.y; acc[3][2] += a.w * w.z; acc[3][3] += a.w * w.w;
        }
        __syncthreads();
    }
    #pragma unroll
    for (int i = 0; i < 4; i++) {
        int m = bm + r0 + i;
        if (m >= NTOK) continue;
        *(float4*)&xz[(size_t)m * (2 * DI) + bn + c0] =
            make_float4(acc[i][0], acc[i][1], acc[i][2], acc[i][3]);
    }
}

// ---------------- xproj with conv fused: dbl += silu(conv(xz)) @ xpw^T, split-K=4 ----------------
// grid (4, 101)
__global__ __launch_bounds__(256) void xproj_conv_k(
    const float* __restrict__ xz,
    const float* __restrict__ cw, const float* __restrict__ cb,
    const float* __restrict__ xpw, float* __restrict__ dbl)
{
    __shared__ float As[96][33];
    __shared__ float Ws[96][48];
    int tid = threadIdx.x;
    int kbase = blockIdx.x * 96;
    int bm = blockIdx.y * 32;
    for (int idx = tid; idx < 96 * 32; idx += 256) {
        int k = idx >> 5, row = idx & 31;
        int m = bm + row;
        float v = 0.f;
        if (m < 2 * NTOK) {
            int dir = m / NTOK;
            int r = m - dir * NTOK;
            int b = r / LSEQ, t = r % LSEQ;
            int ch = kbase + k;
            float a = cb[ch];
            #pragma unroll
            for (int j = 0; j < 4; j++) {
                int tt = t - 3 + j;
                if (tt >= 0) {
                    int st = dir ? (LSEQ - 1 - tt) : tt;
                    a += cw[ch * 4 + j] * xz[((size_t)(b * LSEQ + st)) * (2 * DI) + ch];
                }
            }
            v = silu_f(a);
        }
        As[k][row] = v;
    }
    for (int i = tid; i < 96 * 48; i += 256) {
        int k = i / 48, rr = i % 48;
        Ws[k][rr] = (rr < 44) ? xpw[(size_t)rr * DI + kbase + k] : 0.f;
    }
    __syncthreads();
    int row = tid & 31, cg = tid >> 5;
    int cbase = cg * 6;
    float acc[6] = {};
    #pragma unroll 4
    for (int kk = 0; kk < 96; kk++) {
        float a = As[kk][row];
        #pragma unroll
        for (int j = 0; j < 6; j++) acc[j] += a * Ws[kk][cbase + j];
    }
    int m = bm + row;
    if (m < 2 * NTOK) {
        #pragma unroll
        for (int j = 0; j < 6; j++) {
            int cc = cbase + j;
            if (cc < 44) atomicAdd(&dbl[(size_t)m * 44 + cc], acc[j]);
        }
    }
}

// ---------------- scan pass 1: conv+dt in staging, local scan + chunk product ----------------
// grid (24, NC-1, 8) — all chunks full
__global__ __launch_bounds__(256) void scan_part_k(
    const float* __restrict__ xz, const float* __restrict__ dbl,
    const float* __restrict__ cw, const float* __restrict__ cb,
    const float* __restrict__ dtw, const float* __restrict__ dtb,
    const float* __restrict__ A_log, const float* __restrict__ A_b_log,
    float* __restrict__ hloc, float* __restrict__ Pc)
{
    __shared__ float sdbl[TCH][44];
    __shared__ float sdt[TCH][16];
    __shared__ float sxx[TCH][16];
    __shared__ float sw[16][12];
    __shared__ float sb2[16];
    int dblk = blockIdx.x, chunk = blockIdx.y;
    int db = blockIdx.z;
    int dir = db >> 2, b = db & 3;
    int tid = threadIdx.x;
    int d0 = dblk * 16;
    int t0 = chunk * TCH;
    size_t dof44 = (size_t)db * LSEQ * 44;
    for (int i = tid; i < TCH * 44; i += 256) {
        int t = i / 44, cc = i - t * 44;
        sdbl[t][cc] = dbl[dof44 + (size_t)(t0 + t) * 44 + cc];
    }
    if (tid < 192) { int d = tid / 12, r = tid - d * 12; sw[d][r] = dtw[(size_t)(d0 + d) * 12 + r]; }
    if (tid < 16) sb2[tid] = dtb[d0 + tid];
    for (int i = tid; i < TCH * 16; i += 256) {
        int t = i >> 4, d = i & 15;
        int tq = t0 + t, ch = d0 + d;
        float a = cb[ch];
        #pragma unroll
        for (int j = 0; j < 4; j++) {
            int tt = tq - 3 + j;
            if (tt >= 0) {
                int st = dir ? (LSEQ - 1 - tt) : tt;
                a += cw[ch * 4 + j] * xz[((size_t)(b * LSEQ + st)) * (2 * DI) + ch];
            }
        }
        sxx[t][d] = silu_f(a);
    }
    __syncthreads();
    for (int i = tid; i < TCH * 16; i += 256) {
        int t = i >> 4, d = i & 15;
        float a2 = sb2[d];
        #pragma unroll
        for (int r = 0; r < 12; r++) a2 += sdbl[t][r] * sw[d][r];
        sdt[t][d] = (a2 > 15.f) ? a2 : __logf(1.f + __expf(a2));
    }
    __syncthreads();
    int wave = tid >> 6, lane = tid & 63;
    int dsub = wave * 4 + (lane >> 4);
    int n = lane & 15;
    const float* Al = dir ? A_b_log : A_log;
    float Aval = -__expf(Al[(d0 + dsub) * DS + n]);
    float h = 0.f, P = 1.f;
    #pragma unroll
    for (int i = 0; i < TCH; i++) {
        float dtv = sdt[i][dsub];
        float xv  = sxx[i][dsub];
        float Bv  = sdbl[i][12 + n];
        float dA = __expf(dtv * Aval);
        h = dA * h + (dtv * xv) * Bv;
        P *= dA;
    }
    size_t idx2 = ((size_t)db * NC + chunk) * (DI * DS) + (size_t)(d0 + dsub) * DS + n;
    hloc[idx2] = h;
    Pc[idx2] = P;
}

// ---------------- scan pass 2: conv+dt in staging, compose h_init, rescan, emit y ----------------
// grid (24, NC, 8)
__global__ __launch_bounds__(256) void scan_fix_k(
    const float* __restrict__ xz, const float* __restrict__ dbl,
    const float* __restrict__ cw, const float* __restrict__ cb,
    const float* __restrict__ dtw, const float* __restrict__ dtb,
    const float* __restrict__ A_log, const float* __restrict__ A_b_log,
    const float* __restrict__ Dp,
    const float* __restrict__ hloc, const float* __restrict__ Pc,
    float* __restrict__ yraw)
{
    __shared__ float sdbl[TCH][44];
    __shared__ float sdt[TCH][16];
    __shared__ float sxx[TCH][16];
    __shared__ float sy[TCH][16];
    __shared__ float sw[16][12];
    __shared__ float sb2[16];
    int dblk = blockIdx.x, chunk = blockIdx.y;
    int db = blockIdx.z;
    int dir = db >> 2, b = db & 3;
    int tid = threadIdx.x;
    int d0 = dblk * 16;
    int t0 = chunk * TCH;
    size_t dofD = (size_t)db * LSEQ * DI;
    size_t dof44 = (size_t)db * LSEQ * 44;
    for (int i = tid; i < TCH * 44; i += 256) {
        int t = i / 44, cc = i - t * 44;
        sdbl[t][cc] = ((t0 + t) < LSEQ) ? dbl[dof44 + (size_t)(t0 + t) * 44 + cc] : 0.f;
    }
    if (tid < 192) { int d = tid / 12, r = tid - d * 12; sw[d][r] = dtw[(size_t)(d0 + d) * 12 + r]; }
    if (tid < 16) sb2[tid] = dtb[d0 + tid];
    for (int i = tid; i < TCH * 16; i += 256) {
        int t = i >> 4, d = i & 15;
        int tq = t0 + t, ch = d0 + d;
        float v = 0.f;
        if (tq < LSEQ) {
            float a = cb[ch];
            #pragma unroll
            for (int j = 0; j < 4; j++) {
                int tt = tq - 3 + j;
                if (tt >= 0) {
                    int st = dir ? (LSEQ - 1 - tt) : tt;
                    a += cw[ch * 4 + j] * xz[((size_t)(b * LSEQ + st)) * (2 * DI) + ch];
                }
            }
            v = silu_f(a);
        }
        sxx[t][d] = v;
    }
    __syncthreads();
    for (int i = tid; i < TCH * 16; i += 256) {
        int t = i >> 4, d = i & 15;
        float a2 = sb2[d];
        #pragma unroll
        for (int r = 0; r < 12; r++) a2 += sdbl[t][r] * sw[d][r];
        sdt[t][d] = (a2 > 15.f) ? a2 : __logf(1.f + __expf(a2));
    }
    __syncthreads();
    int wave = tid >> 6, lane = tid & 63;
    int dsub = wave * 4 + (lane >> 4);
    int n = lane & 15;
    const float* Al = dir ? A_b_log : A_log;
    float Aval = -__expf(Al[(d0 + dsub) * DS + n]);
    float Dv = Dp[d0 + dsub];
    // compose initial state: unconditional loads (always in-bounds), masked combine
    float h = 0.f;
    size_t cbase = (size_t)db * NC * (DI * DS) + (size_t)(d0 + dsub) * DS + n;
    #pragma unroll
    for (int j = 0; j < NC - 1; j++) {
        size_t idx = cbase + (size_t)j * (DI * DS);
        float pj = Pc[idx], hj = hloc[idx];
        h = (j < chunk) ? (pj * h + hj) : h;
    }
    #pragma unroll
    for (int i = 0; i < TCH; i++) {
        float dtv = sdt[i][dsub];
        float xv  = sxx[i][dsub];
        float Bv  = sdbl[i][12 + n];
        float Cv  = sdbl[i][28 + n];
        h = __expf(dtv * Aval) * h + (dtv * xv) * Bv;
        float p = h * Cv;
        p += __shfl_xor(p, 1);
        p += __shfl_xor(p, 2);
        p += __shfl_xor(p, 4);
        p += __shfl_xor(p, 8);
        if (n == 0) sy[i][dsub] = p + xv * Dv;
    }
    __syncthreads();
    int len = min(t0 + TCH, LSEQ) - t0;
    for (int idx = tid; idx < len * 16; idx += 256) {
        int t = idx >> 4, d = idx & 15;
        yraw[dofD + (size_t)(t0 + t) * DI + d0 + d] = sy[t][d];
    }
}

// ---------------- fused combine + outproj, 2-stage K (LDS 26KB) ----------------
// hidden += [(yf+yb_rev)*silu(z)] @ opw^T. 32x32 tile, split-K=2. grid (6, 51, 2).
__global__ __launch_bounds__(256) void outproj_k(
    const float* __restrict__ yraw, const float* __restrict__ xz,
    const float* __restrict__ opw, float* __restrict__ hidden)
{
    __shared__ float As[96][34];
    __shared__ float Ws[96][34];
    int tid = threadIdx.x;
    int bn = blockIdx.x * 32;
    int bm = blockIdx.y * 32;
    int kbase = blockIdx.z * 192;
    int row8 = tid >> 3, seg = tid & 7, k0 = seg * 24;
    float a[24], wreg[24];
    int m = bm + row8;
    if (m < NTOK) {
        int b = m / LSEQ, t = m % LSEQ;
        const float* yf = yraw + (size_t)m * DI + kbase + k0;
        const float* yb = yraw + (size_t)(NTOK + b * LSEQ + (LSEQ - 1 - t)) * DI + kbase + k0;
        const float* zp = xz + (size_t)m * (2 * DI) + DI + kbase + k0;
        #pragma unroll
        for (int i = 0; i < 24; i++) {
            float z = zp[i];
            a[i] = (yf[i] + yb[i]) * (z / (1.f + __expf(-z)));
        }
    } else {
        #pragma unroll
        for (int i = 0; i < 24; i++) a[i] = 0.f;
    }
    {
        const float* wp = opw + (size_t)(bn + row8) * DI + kbase + k0;
        #pragma unroll
        for (int i = 0; i < 24; i++) wreg[i] = wp[i];
    }
    int r0 = (tid >> 4) * 2, c0 = (tid & 15) * 2;
    float acc[2][2] = {};
    #pragma unroll
    for (int st = 0; st < 2; st++) {
        if (st) __syncthreads();
        if ((seg >> 2) == st) {
            int kb = k0 - st * 96;
            #pragma unroll
            for (int i = 0; i < 24; i++) {
                As[kb + i][row8] = a[i];
                Ws[kb + i][row8] = wreg[i];
            }
        }
        __syncthreads();
        #pragma unroll 8
        for (int kk = 0; kk < 96; kk++) {
            float2 av = *(const float2*)&As[kk][r0];
            float2 wv = *(const float2*)&Ws[kk][c0];
            acc[0][0] += av.x * wv.x; acc[0][1] += av.x * wv.y;
            acc[1][0] += av.y * wv.x; acc[1][1] += av.y * wv.y;
        }
    }
    #pragma unroll
    for (int i = 0; i < 2; i++) {
        int mm = bm + r0 + i;
        if (mm >= NTOK) continue;
        #pragma unroll
        for (int j = 0; j < 2; j++)
            atomicAdd(&hidden[(size_t)mm * DM + bn + c0 + j], acc[i][j]);
    }
}

// ---------------- final rmsnorm on token 0 + head (mode-switched output) ----------------
__global__ void final_head_k(const float* __restrict__ residual, const float* __restrict__ hidden,
                             const float* __restrict__ norm_f,
                             const float* __restrict__ head_w,
                             const float* __restrict__ head_b,
                             void* __restrict__ out,
                             const unsigned short* __restrict__ probe)
{
    __shared__ float wsum[3];
    __shared__ float hb[DM];
    int b = blockIdx.x;
    int c = threadIdx.x;
    int idx = (b * LSEQ) * DM + c;
    float r = residual[idx] + hidden[idx];
    float s = r * r;
    for (int off = 32; off > 0; off >>= 1) s += __shfl_down(s, off);
    int wave = c >> 6, lane = c & 63;
    if (lane == 0) wsum[wave] = s;
    __syncthreads();
    float tot = wsum[0] + wsum[1] + wsum[2];
    float rms = rsqrtf(tot / (float)DM + 1e-5f);
    hb[c] = r * rms * norm_f[c];
    __syncthreads();
    if (c < NCLS) {
        float acc = head_b[c];
        #pragma unroll 8
        for (int k = 0; k < DM; k++) acc += hb[k] * head_w[c * DM + k];
        if (probe[0] == 0x3F80u)
            ((__hip_bfloat16*)out)[b * NCLS + c] = __float2bfloat16(acc);
        else
            ((float*)out)[b * NCLS + c] = acc;
    }
}

extern "C" void kernel_launch(void* const* d_in, const int* in_sizes, int n_in,
                              void* d_out, int out_size, void* d_ws, size_t ws_size,
                              hipStream_t stream)
{
    (void)in_sizes; (void)n_in; (void)out_size; (void)ws_size;
    // Inputs are fp32 (verified R2-R6: fp32 decode passes with absmax ~0).
    const float* x      = (const float*)d_in[0];
    const float* pe_w   = (const float*)d_in[1];
    const float* pe_b   = (const float*)d_in[2];
    const float* cls    = (const float*)d_in[3];
    const float* pos    = (const float*)d_in[4];
    const float* norm_w = (const float*)d_in[5];
    const float* ipw    = (const float*)d_in[6];
    const float* cw     = (const float*)d_in[7];
    const float* cb     = (const float*)d_in[8];
    const float* xpw    = (const float*)d_in[9];
    const float* dtw    = (const float*)d_in[10];
    const float* dtb    = (const float*)d_in[11];
    const float* A_log  = (const float*)d_in[12];
    const float* A_b_log= (const float*)d_in[13];
    const float* Dp     = (const float*)d_in[14];
    const float* opw    = (const float*)d_in[15];
    const float* norm_f = (const float*)d_in[16];
    const float* head_w = (const float*)d_in[17];
    const float* head_b = (const float*)d_in[18];
    const unsigned short* probe = (const unsigned short*)d_in[14];

    float* ws = (float*)d_ws;
    const size_t nTokDM = (size_t)NTOK * DM;
    const size_t nTokXZ = (size_t)NTOK * 2 * DI;
    const size_t nDirDI = (size_t)2 * NTOK * DI;
    const size_t nDir44 = (size_t)2 * NTOK * 44;
    const size_t nChunk = (size_t)2 * BATCH * NC * DI * DS;  // 786432
    float* resA   = ws;
    float* resB   = resA + nTokDM;
    float* hidden = resB + nTokDM;
    float* hnorm  = hidden + nTokDM;
    float* xz     = hnorm + nTokDM;
    float* dbl    = xz + nTokXZ;
    float* yraw   = dbl + nDir44;
    float* hloc   = yraw + nDirDI;
    float* Pc     = hloc + nChunk;

    patch_embed_k<<<NTOK / 4, DM, 0, stream>>>(x, pe_w, pe_b, cls, pos, resA, hidden);

    for (int l = 0; l < DEPTH; l++) {
        float* rin  = (l & 1) ? resB : resA;
        float* rout = (l & 1) ? resA : resB;

        prenorm_k<<<LSEQ, DM, 0, stream>>>(rin, hidden, rout, hnorm,
                                           norm_w + (size_t)l * DM, dbl);

        gemm_xz_k<<<dim3(12, 26), 256, 0, stream>>>(
            hnorm, ipw + (size_t)l * 2 * DI * DM, xz);

        xproj_conv_k<<<dim3(4, 101), 256, 0, stream>>>(
            xz, cw + (size_t)l * DI * 4, cb + (size_t)l * DI,
            xpw + (size_t)l * 44 * DI, dbl);

        scan_part_k<<<dim3(DI / 16, NC - 1, 2 * BATCH), 256, 0, stream>>>(
            xz, dbl, cw + (size_t)l * DI * 4, cb + (size_t)l * DI,
            dtw + (size_t)l * DI * DR, dtb + (size_t)l * DI,
            A_log + (size_t)l * DI * DS, A_b_log + (size_t)l * DI * DS,
            hloc, Pc);

        scan_fix_k<<<dim3(DI / 16, NC, 2 * BATCH), 256, 0, stream>>>(
            xz, dbl, cw + (size_t)l * DI * 4, cb + (size_t)l * DI,
            dtw + (size_t)l * DI * DR, dtb + (size_t)l * DI,
            A_log + (size_t)l * DI * DS, A_b_log + (size_t)l * DI * DS,
            Dp + (size_t)l * DI, hloc, Pc, yraw);

        outproj_k<<<dim3(6, 51, 2), 256, 0, stream>>>(
            yraw, xz, opw + (size_t)l * DM * DI, hidden);
    }

    final_head_k<<<BATCH, DM, 0, stream>>>(resA, hidden, norm_f, head_w, head_b,
                                           d_out, probe);
}